// Round 1
// 2557.797 us; speedup vs baseline: 1.1876x; 1.1876x over previous
//
#include <hip/hip_runtime.h>

// Two-layer tanh RNN, H=32, B=64, T=16384. Latency-bound sequential scan.
//
// Round-17: remove the LDS round-trip from the recurrence chain.
//  - State broadcast via 32x v_readlane -> SGPRs (pure VALU, no lgkmcnt on
//    the chain) instead of ds_write + 4x ds_read_b128 per step.
//  - Dual-matrix lane split: SGPR operands are wave-uniform, so each lane
//    computes a FULL 32-FMA row dot; lanes 0-31 hold the recurrence matrix
//    row (Whh0 / Whh1), lanes 32-63 hold the secondary matrix row
//    (Wih1 / Wout). One shared FMA pass yields both dots.
//  - u window (A->B handoff), double-buffer parity, barrier-per-32-steps
//    skeleton identical to the proven R14/R16 structure. Hi lanes publish
//    u directly; lo lanes dump to a scratch sink so the store needs no
//    exec-mask dance.
//  - Per-window x chunk is software-pipelined one window ahead (vmcnt off
//    the chain).

#define T_LEN 16384
#define B_SZ  64
#define NW    (T_LEN / 32)   // 512 windows

#if __has_builtin(__builtin_amdgcn_exp2f)
#define EXP2(x) __builtin_amdgcn_exp2f(x)
#else
#define EXP2(x) exp2f(x)
#endif

__device__ __forceinline__ float rl(float v, int lane) {
  return __int_as_float(__builtin_amdgcn_readlane(__float_as_int(v), lane));
}

__device__ __forceinline__ float tanh_fast(float v) {
  // tanh(v) = 1 - 2/(e^{2v}+1); e^{2v} = 2^{v*2*log2(e)}. 5-dep chain.
  float e = EXP2(v * 2.885390082f);
  return fmaf(-2.f, __builtin_amdgcn_rcpf(e + 1.f), 1.f);
}

// Broadcast state (lane k holds h[k], k=0..31) into 32 wave-uniform values.
#define BCAST(dst, src)                                   \
  _Pragma("unroll")                                       \
  for (int k_ = 0; k_ < 32; ++k_) (dst)[k_] = rl((src), k_);

// Full 32-term dot of the per-lane row w[] against uniform hb[].
// 8 accumulators: chain depth 4 FMA + 3-level tree. Seed rides acc 0.
__device__ __forceinline__ float dot32(const float* w, const float* hb,
                                       float seed) {
  float a[8];
#pragma unroll
  for (int j = 0; j < 8; ++j) a[j] = (j == 0) ? seed : 0.f;
#pragma unroll
  for (int k = 0; k < 32; ++k) a[k & 7] = fmaf(w[k], hb[k], a[k & 7]);
  return ((a[0] + a[1]) + (a[2] + a[3])) + ((a[4] + a[5]) + (a[6] + a[7]));
}

__global__ __launch_bounds__(128, 1) void rnn2_kernel(
    const float* __restrict__ x,    const float* __restrict__ hs,
    const float* __restrict__ Wih0, const float* __restrict__ Whh0,
    const float* __restrict__ bih0, const float* __restrict__ bhh0,
    const float* __restrict__ Wih1, const float* __restrict__ Whh1,
    const float* __restrict__ bih1, const float* __restrict__ bhh1,
    const float* __restrict__ Wout, const float* __restrict__ bout,
    float* __restrict__ out)
{
  __shared__ __align__(16) float uwin[2][1024];   // A->B; slot t2*32 + row
  __shared__ __align__(16) float scratch[1024];   // sink for lo-lane publishes

  const int  tid = (int)threadIdx.x;
  const int  wv  = tid >> 6;            // 0 = wave A (h0), 1 = wave B (h1)
  const int  m   = tid & 63;
  const int  r   = m & 31;              // row owned by this lane
  const bool hi  = (m >= 32);           // secondary-matrix half
  const int  b   = (int)blockIdx.x;

  // Per-lane full 32-float row:
  //  A: lo = Whh0[r], hi = Wih1[r].  B: lo = Whh1[r], hi = Wout (row 0, dup).
  const float* pw = (wv == 0) ? (hi ? (Wih1 + r * 32) : (Whh0 + r * 32))
                              : (hi ? Wout : (Whh1 + r * 32));
  float w[32];
#pragma unroll
  for (int k = 0; k < 8; ++k) {
    float4 q = ((const float4*)pw)[k];
    w[4*k] = q.x; w[4*k+1] = q.y; w[4*k+2] = q.z; w[4*k+3] = q.w;
  }

  float xw = 0.f, binv = 0.f;
  if (wv == 0) {
    if (hi) binv = bih1[r] + bhh1[r];            // u seed: b1 (no x term)
    else  { binv = bih0[r] + bhh0[r]; xw = Wih0[r]; }
  }
  const float bo = bout[0];

  // State register: lane k (k<32) holds h[k]. Hi lanes carry garbage copies;
  // BCAST only reads lanes 0..31.
  float hcur = (wv == 0) ? hs[b * 32 + r] : hs[2048 + b * 32 + r];

  // Wave A publish pointers: hi lanes -> uwin row r, lo lanes -> scratch.
  float* up0 = hi ? &uwin[0][r] : &scratch[r];
  float* up1 = hi ? &uwin[1][r] : &scratch[r];

  const float* xb   = x + (size_t)b * T_LEN;
  float*       outp = out + (size_t)b * T_LEN;       // outs[b*T + t]
  float*       hf   = out + (size_t)B_SZ * T_LEN;    // h_final [2,B,H]

  float obuf = 0.f;
  float xcur = 0.f;
  if (wv == 0) xcur = xb[m];            // window 0 chunk (lanes 0..31 used)

  for (int wdx = 0; wdx <= NW; ++wdx) {
    if (wv == 0) {
      if (wdx < NW) {
        // Prefetch next window's x chunk; consumed 32 steps from now.
        float xnext = 0.f;
        if (wdx + 1 < NW) {
          int xi = 32 * (wdx + 1) + m; if (xi > T_LEN - 1) xi = T_LEN - 1;
          xnext = xb[xi];
        }
        float* up = (wdx & 1) ? up1 : up0;
#pragma unroll 4
        for (int t2 = 0; t2 < 32; ++t2) {
          float hb[32];
          BCAST(hb, hcur);                  // h0n(t-1), t = 32*wdx + t2
          float xv   = rl(xcur, t2);        // x(t)   (off-chain)
          float seed = fmaf(xv, xw, binv);  // lo: x*Wih0 + b0; hi: b1
          float acc  = dot32(w, hb, seed);  // lo: tanh arg; hi: u(t-1)
          up[t2 * 32] = acc;                // hi publishes u; lo -> scratch
          hcur = tanh_fast(acc);            // lo lanes: h0n(t)
        }
        xcur = xnext;
      }
    } else {
      if (wdx >= 1) {
        const int wb = wdx - 1;             // steps t = 32*wb-1 .. 32*wb+30
        const float* ub = &uwin[wb & 1][r];
        float uval = ub[0];                 // u(32*wb-1); all lanes broadcast
#pragma unroll 4
        for (int t2 = 0; t2 < 32; ++t2) {
          const int t = 32 * wb - 1 + t2;
          float hb[32];
          BCAST(hb, hcur);                  // h1n(t-1)
          float acc = dot32(w, hb, 0.f);    // lo: Whh1 dot; hi: Wout dot
          float unext = ub[((t2 + 1) & 31) * 32];  // pipelined u-read
          float h1n = tanh_fast(uval + acc);
          obuf = (m == 32 + t2) ? acc : obuf;      // hi lane t2: out(t-1)-bo
          if (t >= 0) hcur = h1n;           // uniform guard (skips wb=0,t2=0)
          uval = unext;
        }
        const int idx = 32 * wb - 2 + r;    // hi lane 32+k holds out(32wb-2+k)
        if (hi && idx >= 0) outp[idx] = obuf + bo;   // coalesced store
      }
    }
    __syncthreads();   // window handoff (uwin parity swap)
  }

  // Epilogue 1 (wave A): publish u(T-1) from h0n(T-1); store h_final L0.
  if (wv == 0) {
    float hb[32];
    BCAST(hb, hcur);                        // h0n(T-1)
    float acc = dot32(w, hb, binv);         // hi: b1 + Wih1 . h0n(T-1)
    if (hi) uwin[0][r] = acc;
    else    hf[b * 32 + r] = hcur;          // h_final layer 0
  }
  __syncthreads();

  // Epilogue 2 (wave B): h1n(T-1), out(T-2), out(T-1), h_final L1.
  if (wv == 1) {
    float uT = uwin[0][r];
    float hb[32];
    BCAST(hb, hcur);                        // h1n(T-2)
    float acc = dot32(w, hb, 0.f);
    if (m == 32) outp[T_LEN - 2] = acc + bo;      // Wout . h1n(T-2)
    float h1T = tanh_fast(uT + acc);
    float hb2[32];
    BCAST(hb2, h1T);                        // h1n(T-1)
    float acc2 = dot32(w, hb2, 0.f);
    if (m == 32) outp[T_LEN - 1] = acc2 + bo;     // Wout . h1n(T-1)
    if (!hi) hf[2048 + b * 32 + r] = h1T;   // h_final layer 1
  }
}

extern "C" void kernel_launch(void* const* d_in, const int* in_sizes, int n_in,
                              void* d_out, int out_size, void* d_ws, size_t ws_size,
                              hipStream_t stream) {
  rnn2_kernel<<<dim3(B_SZ), dim3(128), 0, stream>>>(
      (const float*)d_in[0],  (const float*)d_in[1],  (const float*)d_in[2],
      (const float*)d_in[3],  (const float*)d_in[4],  (const float*)d_in[5],
      (const float*)d_in[6],  (const float*)d_in[7],  (const float*)d_in[8],
      (const float*)d_in[9],  (const float*)d_in[10], (const float*)d_in[11],
      (float*)d_out);
}

// Round 2
// 2011.964 us; speedup vs baseline: 1.5098x; 1.2713x over previous
//
#include <hip/hip_runtime.h>

// Two-layer tanh RNN, H=32, B=64, T=16384. Latency-bound sequential scan.
//
// Round-18: halve the per-step issue count with f16-packed broadcast + dot2.
// R17 analysis: step is issue-bound (~80 VALU instrs/wave/step: 32 readlane
// + 32 fma dominate). This round packs the state into f16 PAIRS so that:
//  - broadcast = 16 v_readlane (was 32): one DPP pair-swap + cvt_pk forms
//    (h[2j], h[2j+1]) in even lane 2j; readlane even lanes only.
//  - dot = 16 v_dot2_f32_f16 (was 32 v_fma), f32 accumulation.
//  - dual-matrix lane split unchanged (lo lanes: recurrence row, hi lanes:
//    secondary row share the same instructions).
// Precision: h and W quantized to f16 (RNE); seed/x-term, u handoff, tanh,
// accumulators all stay f32. Expected absmax drift ~+3..8e-4.
// Skeleton (u window ring, barrier per 32-step window, epilogues) identical
// to the passing R17.

#define T_LEN 16384
#define B_SZ  64
#define NW    (T_LEN / 32)   // 512 windows

#if __has_builtin(__builtin_amdgcn_exp2f)
#define EXP2(x) __builtin_amdgcn_exp2f(x)
#else
#define EXP2(x) exp2f(x)
#endif

typedef _Float16 h2 __attribute__((ext_vector_type(2)));

__device__ __forceinline__ float rl(float v, int lane) {
  return __int_as_float(__builtin_amdgcn_readlane(__float_as_int(v), lane));
}

__device__ __forceinline__ h2 rl_h2(h2 v, int lane) {
  int o = __builtin_amdgcn_readlane(__builtin_bit_cast(int, v), lane);
  return __builtin_bit_cast(h2, o);
}

// quad_perm([1,0,3,2]): each lane sees its pair-neighbor's value.
__device__ __forceinline__ float pair_swap(float v) {
  int t = __builtin_amdgcn_update_dpp(0, __float_as_int(v), 0xB1, 0xF, 0xF, true);
  return __int_as_float(t);
}

__device__ __forceinline__ float tanh_fast(float v) {
  // tanh(v) = 1 - 2/(e^{2v}+1); e^{2v} = 2^{v*2*log2(e)}. 5-dep chain.
  float e = EXP2(v * 2.885390082f);
  return fmaf(-2.f, __builtin_amdgcn_rcpf(e + 1.f), 1.f);
}

#if __has_builtin(__builtin_amdgcn_fdot2)
#define FDOT2(a, b, c) __builtin_amdgcn_fdot2((a), (b), (c), false)
#else
#define FDOT2(a, b, c) \
  fmaf((float)(a).x, (float)(b).x, fmaf((float)(a).y, (float)(b).y, (c)))
#endif

// Pack this lane's state with its pair-neighbor: even lane 2j ends up with
// (h[2j], h[2j+1]). Odd/hi lanes hold swapped/garbage pairs — never read.
__device__ __forceinline__ h2 pack_state(float hcur) {
  float hsw = pair_swap(hcur);
  h2 p;
  p.x = (_Float16)hcur;
  p.y = (_Float16)hsw;
  return p;
}

// Broadcast 16 packed pairs from even lanes 0,2,...,30 into uniform regs.
#define BCASTH(dst, src_pk)                                  \
  _Pragma("unroll")                                          \
  for (int j_ = 0; j_ < 16; ++j_) (dst)[j_] = rl_h2((src_pk), 2 * j_);

// 32-term dot via 16 dot2, 4 accumulators (depth 4) + 2-level tree.
__device__ __forceinline__ float dot32h(const h2* w, const h2* hb, float seed) {
  float a0 = seed, a1 = 0.f, a2 = 0.f, a3 = 0.f;
#pragma unroll
  for (int j = 0; j < 4; ++j) {
    a0 = FDOT2(w[4 * j + 0], hb[4 * j + 0], a0);
    a1 = FDOT2(w[4 * j + 1], hb[4 * j + 1], a1);
    a2 = FDOT2(w[4 * j + 2], hb[4 * j + 2], a2);
    a3 = FDOT2(w[4 * j + 3], hb[4 * j + 3], a3);
  }
  return (a0 + a1) + (a2 + a3);
}

__global__ __launch_bounds__(128, 1) void rnn2_kernel(
    const float* __restrict__ x,    const float* __restrict__ hs,
    const float* __restrict__ Wih0, const float* __restrict__ Whh0,
    const float* __restrict__ bih0, const float* __restrict__ bhh0,
    const float* __restrict__ Wih1, const float* __restrict__ Whh1,
    const float* __restrict__ bih1, const float* __restrict__ bhh1,
    const float* __restrict__ Wout, const float* __restrict__ bout,
    float* __restrict__ out)
{
  __shared__ __align__(16) float uwin[2][1024];   // A->B; slot t2*32 + row
  __shared__ __align__(16) float scratch[1024];   // sink for lo-lane publishes

  const int  tid = (int)threadIdx.x;
  const int  wv  = tid >> 6;            // 0 = wave A (h0), 1 = wave B (h1)
  const int  m   = tid & 63;
  const int  r   = m & 31;              // row owned by this lane
  const bool hi  = (m >= 32);           // secondary-matrix half
  const int  b   = (int)blockIdx.x;

  // Per-lane full 32-float row, packed to 16 f16 pairs:
  //  A: lo = Whh0[r], hi = Wih1[r].  B: lo = Whh1[r], hi = Wout (row 0, dup).
  const float* pw = (wv == 0) ? (hi ? (Wih1 + r * 32) : (Whh0 + r * 32))
                              : (hi ? Wout : (Whh1 + r * 32));
  h2 w[16];
#pragma unroll
  for (int k = 0; k < 8; ++k) {
    float4 q = ((const float4*)pw)[k];
    w[2 * k].x     = (_Float16)q.x;
    w[2 * k].y     = (_Float16)q.y;
    w[2 * k + 1].x = (_Float16)q.z;
    w[2 * k + 1].y = (_Float16)q.w;
  }

  float xw = 0.f, binv = 0.f;
  if (wv == 0) {
    if (hi) binv = bih1[r] + bhh1[r];            // u seed: b1 (no x term)
    else  { binv = bih0[r] + bhh0[r]; xw = Wih0[r]; }
  }
  const float bo = bout[0];

  // State register: lane k (k<32) holds h[k] in f32. Hi lanes carry garbage
  // copies; pack_state/BCASTH only read lanes 0..31 (even lanes).
  float hcur = (wv == 0) ? hs[b * 32 + r] : hs[2048 + b * 32 + r];

  // Wave A publish pointers: hi lanes -> uwin row r, lo lanes -> scratch.
  float* up0 = hi ? &uwin[0][r] : &scratch[r];
  float* up1 = hi ? &uwin[1][r] : &scratch[r];

  const float* xb   = x + (size_t)b * T_LEN;
  float*       outp = out + (size_t)b * T_LEN;       // outs[b*T + t]
  float*       hf   = out + (size_t)B_SZ * T_LEN;    // h_final [2,B,H]

  float obuf = 0.f;
  float xcur = 0.f;
  if (wv == 0) xcur = xb[m];            // window 0 chunk (lanes 0..31 used)

  for (int wdx = 0; wdx <= NW; ++wdx) {
    if (wv == 0) {
      if (wdx < NW) {
        // Prefetch next window's x chunk; consumed 32 steps from now.
        float xnext = 0.f;
        if (wdx + 1 < NW) {
          int xi = 32 * (wdx + 1) + m; if (xi > T_LEN - 1) xi = T_LEN - 1;
          xnext = xb[xi];
        }
        float* up = (wdx & 1) ? up1 : up0;
#pragma unroll 4
        for (int t2 = 0; t2 < 32; ++t2) {
          h2 hpk = pack_state(hcur);        // h0n(t-1) packed pairs
          h2 hb[16];
          BCASTH(hb, hpk);
          float xv   = rl(xcur, t2);        // x(t)   (off-chain)
          float seed = fmaf(xv, xw, binv);  // lo: x*Wih0 + b0; hi: b1
          float acc  = dot32h(w, hb, seed); // lo: tanh arg; hi: u(t-1)
          up[t2 * 32] = acc;                // hi publishes u; lo -> scratch
          hcur = tanh_fast(acc);            // lo lanes: h0n(t)
        }
        xcur = xnext;
      }
    } else {
      if (wdx >= 1) {
        const int wb = wdx - 1;             // steps t = 32*wb-1 .. 32*wb+30
        const float* ub = &uwin[wb & 1][r];
        float uval = ub[0];                 // u(32*wb-1); all lanes broadcast
#pragma unroll 4
        for (int t2 = 0; t2 < 32; ++t2) {
          const int t = 32 * wb - 1 + t2;
          h2 hpk = pack_state(hcur);        // h1n(t-1) packed pairs
          h2 hb[16];
          BCASTH(hb, hpk);
          float acc = dot32h(w, hb, 0.f);   // lo: Whh1 dot; hi: Wout dot
          float unext = ub[((t2 + 1) & 31) * 32];  // pipelined u-read
          float h1n = tanh_fast(uval + acc);
          obuf = (m == 32 + t2) ? acc : obuf;      // hi lane t2: out(t-1)-bo
          if (t >= 0) hcur = h1n;           // uniform guard (skips wb=0,t2=0)
          uval = unext;
        }
        const int idx = 32 * wb - 2 + r;    // hi lane 32+k holds out(32wb-2+k)
        if (hi && idx >= 0) outp[idx] = obuf + bo;   // coalesced store
      }
    }
    __syncthreads();   // window handoff (uwin parity swap)
  }

  // Epilogue 1 (wave A): publish u(T-1) from h0n(T-1); store h_final L0.
  if (wv == 0) {
    h2 hpk = pack_state(hcur);              // h0n(T-1)
    h2 hb[16];
    BCASTH(hb, hpk);
    float acc = dot32h(w, hb, binv);        // hi: b1 + Wih1 . h0n(T-1)
    if (hi) uwin[0][r] = acc;
    else    hf[b * 32 + r] = hcur;          // h_final layer 0 (full f32)
  }
  __syncthreads();

  // Epilogue 2 (wave B): h1n(T-1), out(T-2), out(T-1), h_final L1.
  if (wv == 1) {
    float uT = uwin[0][r];
    h2 hpk = pack_state(hcur);              // h1n(T-2)
    h2 hb[16];
    BCASTH(hb, hpk);
    float acc = dot32h(w, hb, 0.f);
    if (m == 32) outp[T_LEN - 2] = acc + bo;      // Wout . h1n(T-2)
    float h1T = tanh_fast(uT + acc);
    h2 hpk2 = pack_state(h1T);              // h1n(T-1)
    h2 hb2[16];
    BCASTH(hb2, hpk2);
    float acc2 = dot32h(w, hb2, 0.f);
    if (m == 32) outp[T_LEN - 1] = acc2 + bo;     // Wout . h1n(T-1)
    if (!hi) hf[2048 + b * 32 + r] = h1T;   // h_final layer 1 (full f32)
  }
}

extern "C" void kernel_launch(void* const* d_in, const int* in_sizes, int n_in,
                              void* d_out, int out_size, void* d_ws, size_t ws_size,
                              hipStream_t stream) {
  rnn2_kernel<<<dim3(B_SZ), dim3(128), 0, stream>>>(
      (const float*)d_in[0],  (const float*)d_in[1],  (const float*)d_in[2],
      (const float*)d_in[3],  (const float*)d_in[4],  (const float*)d_in[5],
      (const float*)d_in[6],  (const float*)d_in[7],  (const float*)d_in[8],
      (const float*)d_in[9],  (const float*)d_in[10], (const float*)d_in[11],
      (float*)d_out);
}